// Round 16
// baseline (454.443 us; speedup 1.0000x reference)
//
#include <hip/hip_runtime.h>
#include <hip/hip_fp16.h>
#include <hip/hip_cooperative_groups.h>

namespace cg = cooperative_groups;

#define D 64
#define BSH 9               // bucket = dst >> 9 : 512 nodes per bucket
#define SPLIT_CH 2048       // edges per split chunk (16.25 KB union LDS)
#define QSCALE 0.18033688f  // 0.125 * log2(e)

typedef _Float16 f16x2 __attribute__((ext_vector_type(2)));
typedef _Float16 f16x8 __attribute__((ext_vector_type(8)));
typedef float f32x4 __attribute__((ext_vector_type(4)));

__device__ __forceinline__ float fdot2f(f16x2 a, f16x2 b, float c) {
#if __has_builtin(__builtin_amdgcn_fdot2)
    return __builtin_amdgcn_fdot2(a, b, c, false);
#else
    return fmaf((float)a.x, (float)b.x, fmaf((float)a.y, (float)b.y, c));
#endif
}

__device__ __forceinline__ f16x2 shxor_h2(f16x2 v, int m) {
    int i = __builtin_bit_cast(int, v);
    i = __shfl_xor(i, m);
    return __builtin_bit_cast(f16x2, i);
}

__device__ __forceinline__ unsigned packh2(float a, float b) {
    __half2 h = __floats2half2_rn(a, b);
    return __builtin_bit_cast(unsigned, h);
}

union SMem {
    int hist0[256];                                    // phase 0
    struct {                                           // phase 1 split: 16.25 KB
        unsigned vals[SPLIT_CH];
        unsigned char bkt[SPLIT_CH];
        int hist[256], start[256], cur[256], base[256], s2[256], sg[256];
    } sp;
    struct { __align__(16) _Float16 xsh[16][72]; } lin; // phase 1 linear: 2.3 KB
    struct { int h[512], ex[512], cur[512], sA[256]; } ns; // phase 2: 7 KB
};

// ---------------------------------------------------------------------------
// Mega-kernel: all stages with guaranteed co-residency (cooperative launch).
// Phase 0: W-pack + bias + bucket hist.  Phase 1: split || MFMA linear.
// Phase 2: per-bucket nodesort.  Phase 3: attention (+skip already in out).
// ---------------------------------------------------------------------------
__global__ __launch_bounds__(256, 8) void k_mega(
    const float* __restrict__ x, const int* __restrict__ ei,
    const float* __restrict__ Wq, const float* __restrict__ bq,
    const float* __restrict__ Wk, const float* __restrict__ bk,
    const float* __restrict__ Wv, const float* __restrict__ bv,
    const float* __restrict__ Wsk, const float* __restrict__ bsk,
    unsigned* __restrict__ wpk, float* __restrict__ ball,
    int* __restrict__ ghist, int* __restrict__ gcur0,
    unsigned* __restrict__ qh, unsigned* __restrict__ kvh,
    unsigned* __restrict__ epack, int* __restrict__ esrc,
    int* __restrict__ endoff, float* __restrict__ out,
    int n, int e_cnt)
{
    __shared__ SMem sm;
    cg::grid_group gg = cg::this_grid();
    const int nb  = (int)gridDim.x;
    const int bid = (int)blockIdx.x;
    const int t   = (int)threadIdx.x;

    const int NLIN   = (n + 15) >> 4;
    const int NSPLIT = (e_cnt + SPLIT_CH - 1) / SPLIT_CH;
    const int nbkt   = (n + 511) >> BSH;

    // ================= Phase 0: W-pack + bias + bucket histogram =========
    if (bid < 32) {
        const int u    = bid * 256 + t;
        const int i2   = u & 3;
        const int lane = (u >> 2) & 63;
        const int ks   = (u >> 8) & 1;
        const int mt   = u >> 9;
        const int ncol = mt * 16 + (lane & 15);
        const int k0   = ks * 32 + ((lane >> 4) << 3) + (i2 << 1);
        const float* W; int c; float sc = 1.f;
        if      (ncol <  64) { W = Wq;  c = ncol;       sc = QSCALE; }
        else if (ncol < 128) { W = Wk;  c = ncol - 64;  }
        else if (ncol < 192) { W = Wv;  c = ncol - 128; }
        else                 { W = Wsk; c = ncol - 192; }
        wpk[u] = packh2(W[k0 * 64 + c] * sc, W[(k0 + 1) * 64 + c] * sc);
    } else if (bid == 32) {
        float b;
        if      (t <  64) b = bq[t] * QSCALE;
        else if (t < 128) b = bk[t - 64];
        else if (t < 192) b = bv[t - 128];
        else              b = bsk[t - 192];
        ball[t] = b;
    }
    {
        int* h = sm.hist0;
        h[t] = 0;
        __syncthreads();
        for (int i = bid * 256 + t; i < e_cnt; i += nb * 256)
            atomicAdd(&h[ei[e_cnt + i] >> BSH], 1);
        __syncthreads();
        if (h[t]) atomicAdd(&ghist[t], h[t]);
    }
    gg.sync();

    // ================= Phase 1: split || MFMA linear ======================
    const int SP = min(NSPLIT, nb >> 1);
    if (bid < SP) {
        // ---- split role (grid-strided chunks) ----
        for (int cidx = bid; cidx < NSPLIT; cidx += SP) {
            const int e0  = cidx * SPLIT_CH;
            const int cnt = min(SPLIT_CH, e_cnt - e0);

            sm.sp.hist[t] = 0;
            __syncthreads();
            for (int i = t; i < cnt; i += 256)
                atomicAdd(&sm.sp.hist[ei[e_cnt + e0 + i] >> BSH], 1);
            __syncthreads();

            {   // local scan + ghist self-scan + global reserve
                const int v = sm.sp.hist[t];
                const int g = ghist[t];
                sm.sp.s2[t] = v;
                sm.sp.sg[t] = g;
                __syncthreads();
                for (int off = 1; off < 256; off <<= 1) {
                    const int a1 = (t >= off) ? sm.sp.s2[t - off] : 0;
                    const int a2 = (t >= off) ? sm.sp.sg[t - off] : 0;
                    __syncthreads();
                    sm.sp.s2[t] += a1;
                    sm.sp.sg[t] += a2;
                    __syncthreads();
                }
                sm.sp.start[t] = sm.sp.s2[t] - v;
                sm.sp.cur[t]   = sm.sp.s2[t] - v;
                sm.sp.base[t]  = v ? (sm.sp.sg[t] - g + atomicAdd(&gcur0[t], v)) : 0;
            }
            __syncthreads();

            for (int i = t; i < cnt; i += 256) {
                const int s = ei[e0 + i];
                const int d = ei[e_cnt + e0 + i];
                const int b = d >> BSH;
                const int r = atomicAdd(&sm.sp.cur[b], 1);
                sm.sp.vals[r] = ((unsigned)s << BSH) | (unsigned)(d & 511);
                sm.sp.bkt[r]  = (unsigned char)b;
            }
            __syncthreads();

            for (int i = t; i < cnt; i += 256) {
                const int b = sm.sp.bkt[i];
                epack[sm.sp.base[b] + (i - sm.sp.start[b])] = sm.sp.vals[i];
            }
            __syncthreads();   // LDS safe for next chunk
        }
    } else {
        // ---- MFMA linear role (grid-strided 16-node tiles) ----
        const int lb  = bid - SP;
        const int nlb = nb - SP;
        const uint4* wpk4 = (const uint4*)wpk;
        for (int tile = lb; tile < NLIN; tile += nlb) {
            const int node0 = tile * 16;
            {
                const float4* xg = (const float4*)(x + (size_t)node0 * 64);
                const int row = t >> 4, c4 = (t & 15) << 2;
                if (node0 + row < n) {
                    const float4 v = xg[t];
                    f16x2* dst = (f16x2*)&sm.lin.xsh[row][c4];
                    dst[0] = f16x2{(_Float16)v.x, (_Float16)v.y};
                    dst[1] = f16x2{(_Float16)v.z, (_Float16)v.w};
                }
            }
            __syncthreads();

            const int w  = t >> 6;      // 0=q 1=k 2=v 3=skip
            const int l  = t & 63;
            const int nd = l & 15;
            const int kg = l >> 4;

            f32x4 acc0 = {0.f, 0.f, 0.f, 0.f};
            f32x4 acc1 = acc0, acc2 = acc0, acc3 = acc0;
#pragma unroll
            for (int ks = 0; ks < 2; ++ks) {
                const f16x8 bfrag = *(const f16x8*)&sm.lin.xsh[nd][ks * 32 + kg * 8];
                const int fb = (w * 4 * 2 + ks) * 64 + l;
                const f16x8 a0 = __builtin_bit_cast(f16x8, wpk4[fb]);
                const f16x8 a1 = __builtin_bit_cast(f16x8, wpk4[fb + 128]);
                const f16x8 a2 = __builtin_bit_cast(f16x8, wpk4[fb + 256]);
                const f16x8 a3 = __builtin_bit_cast(f16x8, wpk4[fb + 384]);
                acc0 = __builtin_amdgcn_mfma_f32_16x16x32_f16(a0, bfrag, acc0, 0, 0, 0);
                acc1 = __builtin_amdgcn_mfma_f32_16x16x32_f16(a1, bfrag, acc1, 0, 0, 0);
                acc2 = __builtin_amdgcn_mfma_f32_16x16x32_f16(a2, bfrag, acc2, 0, 0, 0);
                acc3 = __builtin_amdgcn_mfma_f32_16x16x32_f16(a3, bfrag, acc3, 0, 0, 0);
            }

            const int node = node0 + nd;
            if (node < n) {
                f32x4 accs[4] = {acc0, acc1, acc2, acc3};
#pragma unroll
                for (int m4 = 0; m4 < 4; ++m4) {
                    const int gc = (w * 4 + m4) * 16 + kg * 4;
                    const float4 bb = ((const float4*)ball)[gc >> 2];
                    const float v0 = accs[m4][0] + bb.x;
                    const float v1 = accs[m4][1] + bb.y;
                    const float v2 = accs[m4][2] + bb.z;
                    const float v3 = accs[m4][3] + bb.w;
                    if (w == 3) {
                        ((float4*)out)[(size_t)node * 16 + ((gc - 192) >> 2)] =
                            make_float4(v0, v1, v2, v3);
                    } else {
                        uint2 u;
                        u.x = packh2(v0, v1);
                        u.y = packh2(v2, v3);
                        if (w == 0)
                            ((uint2*)qh)[(size_t)node * 16 + (gc >> 2)] = u;
                        else if (w == 1)
                            ((uint2*)kvh)[(size_t)node * 32 + ((gc - 64) >> 2)] = u;
                        else
                            ((uint2*)kvh)[(size_t)node * 32 + 16 + ((gc - 128) >> 2)] = u;
                    }
                }
            }
            __syncthreads();   // LDS safe for next tile
        }
    }
    gg.sync();

    // ================= Phase 2: per-bucket node sort (256 thr, 512 slots) =
    if (bid < nbkt) {
        int* h   = sm.ns.h;
        int* ex  = sm.ns.ex;
        int* cur = sm.ns.cur;
        int* sA  = sm.ns.sA;

        sA[t] = ghist[t];
        __syncthreads();
        for (int off = 1; off < 256; off <<= 1) {
            const int add = (t >= off) ? sA[t - off] : 0;
            __syncthreads();
            sA[t] += add;
            __syncthreads();
        }
        const int base = (bid == 0) ? 0 : sA[bid - 1];
        const int cnt  = ghist[bid];

        h[t] = 0; h[t + 256] = 0;
        __syncthreads();
        for (int i = t; i < cnt; i += 256)
            atomicAdd(&h[epack[base + i] & 511], 1);
        __syncthreads();

        const int p0 = h[2 * t], p1 = h[2 * t + 1];
        sA[t] = p0 + p1;
        __syncthreads();
        for (int off = 1; off < 256; off <<= 1) {
            const int add = (t >= off) ? sA[t - off] : 0;
            __syncthreads();
            sA[t] += add;
            __syncthreads();
        }
        const int exc = sA[t] - (p0 + p1);
        ex[2 * t]     = exc;
        ex[2 * t + 1] = exc + p0;
        cur[2 * t]     = exc;
        cur[2 * t + 1] = exc + p0;
        const int node0 = (bid << BSH) + 2 * t;
        if (node0     < n) endoff[node0]     = base + exc + p0;
        if (node0 + 1 < n) endoff[node0 + 1] = base + exc + p0 + p1;
        __syncthreads();

        for (int i = t; i < cnt; i += 256) {
            const unsigned p = epack[base + i];
            const int r = atomicAdd(&cur[p & 511], 1);
            esrc[base + r] = (int)(p >> BSH);
        }
    }
    gg.sync();

    // ================= Phase 3: attention (grid-stride over node quads) ===
    const int nq = (n + 3) >> 2;
    const uint4* qh4 = (const uint4*)qh;
    const uint4* kv4 = (const uint4*)kvh;
    for (int qd = bid; qd < nq; qd += nb) {
        const int node = qd * 4 + (t >> 6);
        if (node < n) {
            const int lane = t & 63;
            const int g = lane >> 3;
            const int l = lane & 7;

            const int beg = (node == 0) ? 0 : endoff[node - 1];
            const int end = endoff[node];
            const int last = end - 1;

            float4 o0 = make_float4(0.f, 0.f, 0.f, 0.f);
            float4 o1 = o0;
            if (g == 0) {
                o0 = ((const float4*)out)[(size_t)node * 16 + 2 * l];
                o1 = ((const float4*)out)[(size_t)node * 16 + 2 * l + 1];
            }

            const uint4 qu = qh4[(size_t)node * 8 + l];
            const f16x2* qp = (const f16x2*)&qu;

            f16x2 a0 = {(_Float16)0.f, (_Float16)0.f};
            f16x2 a1 = a0, a2 = a0, a3 = a0;
            float den = 0.f;

            int b2 = beg;
            for (; end - b2 > 8; b2 += 16) {
                const int iA = b2 + 2 * g;
                const int iB = iA + 1;
                const int sA_ = esrc[min(iA, last)];
                const int sB_ = esrc[min(iB, last)];
                const uint4 kuA = kv4[(size_t)sA_ * 16 + l];
                const uint4 vuA = kv4[(size_t)sA_ * 16 + 8 + l];
                const uint4 kuB = kv4[(size_t)sB_ * 16 + l];
                const uint4 vuB = kv4[(size_t)sB_ * 16 + 8 + l];
                const f16x2* kpA = (const f16x2*)&kuA;
                const f16x2* vpA = (const f16x2*)&vuA;
                const f16x2* kpB = (const f16x2*)&kuB;
                const f16x2* vpB = (const f16x2*)&vuB;

                float dA = fdot2f(qp[0], kpA[0], 0.f);
                float dB = fdot2f(qp[0], kpB[0], 0.f);
                dA = fdot2f(qp[1], kpA[1], dA);
                dB = fdot2f(qp[1], kpB[1], dB);
                dA = fdot2f(qp[2], kpA[2], dA);
                dB = fdot2f(qp[2], kpB[2], dB);
                dA = fdot2f(qp[3], kpA[3], dA);
                dB = fdot2f(qp[3], kpB[3], dB);
                dA += __shfl_xor(dA, 1);  dB += __shfl_xor(dB, 1);
                dA += __shfl_xor(dA, 2);  dB += __shfl_xor(dB, 2);
                dA += __shfl_xor(dA, 4);  dB += __shfl_xor(dB, 4);

                const float eA = (iA < end) ? exp2f(dA) : 0.f;
                const float eB = (iB < end) ? exp2f(dB) : 0.f;
                den += eA + eB;
                const _Float16 ehA = (_Float16)eA;
                const _Float16 ehB = (_Float16)eB;
                const f16x2 e2A = {ehA, ehA};
                const f16x2 e2B = {ehB, ehB};
                a0 += e2A * vpA[0];  a0 += e2B * vpB[0];
                a1 += e2A * vpA[1];  a1 += e2B * vpB[1];
                a2 += e2A * vpA[2];  a2 += e2B * vpB[2];
                a3 += e2A * vpA[3];  a3 += e2B * vpB[3];
            }
            for (; b2 < end; b2 += 8) {
                const int i = b2 + g;
                const int s = esrc[min(i, last)];
                const uint4 ku = kv4[(size_t)s * 16 + l];
                const uint4 vu = kv4[(size_t)s * 16 + 8 + l];
                const f16x2* kp = (const f16x2*)&ku;
                const f16x2* vp = (const f16x2*)&vu;

                float d = fdot2f(qp[0], kp[0], 0.f);
                d = fdot2f(qp[1], kp[1], d);
                d = fdot2f(qp[2], kp[2], d);
                d = fdot2f(qp[3], kp[3], d);
                d += __shfl_xor(d, 1);
                d += __shfl_xor(d, 2);
                d += __shfl_xor(d, 4);

                const float e = (i < end) ? exp2f(d) : 0.f;
                den += e;
                const _Float16 eh = (_Float16)e;
                const f16x2 e2 = {eh, eh};
                a0 += e2 * vp[0];
                a1 += e2 * vp[1];
                a2 += e2 * vp[2];
                a3 += e2 * vp[3];
            }

#pragma unroll
            for (int m = 8; m <= 32; m <<= 1) {
                den += __shfl_xor(den, m);
                a0 += shxor_h2(a0, m);
                a1 += shxor_h2(a1, m);
                a2 += shxor_h2(a2, m);
                a3 += shxor_h2(a3, m);
            }

            if (g == 0) {
                const float inv = 1.f / (den + 1e-16f);
                float4 r0, r1;
                r0.x = o0.x + (float)a0.x * inv;
                r0.y = o0.y + (float)a0.y * inv;
                r0.z = o0.z + (float)a1.x * inv;
                r0.w = o0.w + (float)a1.y * inv;
                r1.x = o1.x + (float)a2.x * inv;
                r1.y = o1.y + (float)a2.y * inv;
                r1.z = o1.z + (float)a3.x * inv;
                r1.w = o1.w + (float)a3.y * inv;
                ((float4*)out)[(size_t)node * 16 + 2 * l]     = r0;
                ((float4*)out)[(size_t)node * 16 + 2 * l + 1] = r1;
            }
        }
    }
}

// ---------------------------------------------------------------------------
extern "C" void kernel_launch(void* const* d_in, const int* in_sizes, int n_in,
                              void* d_out, int out_size, void* d_ws, size_t ws_size,
                              hipStream_t stream)
{
    const float* x   = (const float*)d_in[0];
    const int*   ei  = (const int*)d_in[1];
    // d_in[2] = edge_type, unused by the reference forward
    const float* Wq  = (const float*)d_in[3];
    const float* bq  = (const float*)d_in[4];
    const float* Wk  = (const float*)d_in[5];
    const float* bk  = (const float*)d_in[6];
    const float* Wv  = (const float*)d_in[7];
    const float* bv  = (const float*)d_in[8];
    const float* Wsk = (const float*)d_in[9];
    const float* bsk = (const float*)d_in[10];
    float* out = (float*)d_out;

    int n     = in_sizes[0] / D;   // 100000
    int e_cnt = in_sizes[1] / 2;   // 1200000

    // workspace layout
    unsigned* qh     = (unsigned*)d_ws;                   // n*32 u32
    unsigned* kvh    = qh + (size_t)n * 32;               // n*64 u32
    int*      esrc   = (int*)(kvh + (size_t)n * 64);
    unsigned* epack  = (unsigned*)(esrc + e_cnt);
    int*      endoff = (int*)(epack + e_cnt);
    int*      ghist  = endoff + n;
    int*      gcur0  = ghist + 256;
    float*    ball   = (float*)(gcur0 + 256);
    unsigned* wpk    = (unsigned*)(ball + 256);           // 8192 u32

    hipMemsetAsync(ghist, 0, 512 * sizeof(int), stream);  // ghist + gcur0

    int mpc = 0;
    hipOccupancyMaxActiveBlocksPerMultiprocessor(&mpc, k_mega, 256, 0);
    if (mpc < 1) mpc = 1;
    int grid = mpc * 256;                                 // 256 CUs on MI355X
    if (grid > 2048) grid = 2048;

    void* args[] = {
        (void*)&x, (void*)&ei,
        (void*)&Wq, (void*)&bq, (void*)&Wk, (void*)&bk,
        (void*)&Wv, (void*)&bv, (void*)&Wsk, (void*)&bsk,
        (void*)&wpk, (void*)&ball, (void*)&ghist, (void*)&gcur0,
        (void*)&qh, (void*)&kvh, (void*)&epack, (void*)&esrc,
        (void*)&endoff, (void*)&out, (void*)&n, (void*)&e_cnt
    };
    hipLaunchCooperativeKernel((const void*)k_mega, dim3(grid), dim3(256),
                               args, 0, stream);
}

// Round 17
// 124.058 us; speedup vs baseline: 3.6632x; 3.6632x over previous
//
#include <hip/hip_runtime.h>
#include <hip/hip_fp16.h>

#define D 64
#define BSH 9               // bucket = dst >> 9 : 512 nodes per bucket
#define SPLIT_CH 4096       // edges per split-role block
#define NH 512              // histogram-role blocks in k_prep
#define QSCALE 0.18033688f  // 0.125 * log2(e)

typedef _Float16 f16x2 __attribute__((ext_vector_type(2)));
typedef _Float16 f16x8 __attribute__((ext_vector_type(8)));
typedef float f32x4 __attribute__((ext_vector_type(4)));

__device__ __forceinline__ float fdot2f(f16x2 a, f16x2 b, float c) {
#if __has_builtin(__builtin_amdgcn_fdot2)
    return __builtin_amdgcn_fdot2(a, b, c, false);
#else
    return fmaf((float)a.x, (float)b.x, fmaf((float)a.y, (float)b.y, c));
#endif
}

__device__ __forceinline__ f16x2 shxor_h2(f16x2 v, int m) {
    int i = __builtin_bit_cast(int, v);
    i = __shfl_xor(i, m);
    return __builtin_bit_cast(f16x2, i);
}

__device__ __forceinline__ unsigned packh2(float a, float b) {
    __half2 h = __floats2half2_rn(a, b);
    return __builtin_bit_cast(unsigned, h);
}

// ---------------------------------------------------------------------------
// K0: prep.  Blocks 0-31: W fragment pack.  Block 32: bias table.
// Blocks 33..33+NH: LDS-aggregated bucket histogram of dst.
// ghist/gcur0 pre-zeroed by hipMemsetAsync.
// ---------------------------------------------------------------------------
__global__ __launch_bounds__(256) void k_prep(
    const float* __restrict__ Wq, const float* __restrict__ Wk,
    const float* __restrict__ Wv, const float* __restrict__ Wsk,
    const float* __restrict__ bq, const float* __restrict__ bk,
    const float* __restrict__ bv, const float* __restrict__ bsk,
    const int* __restrict__ ei, unsigned* __restrict__ wpk,
    float* __restrict__ ball, int* __restrict__ ghist, int e_cnt)
{
    const int t = threadIdx.x;
    if (blockIdx.x < 32) {
        const int u    = blockIdx.x * 256 + t;
        const int i2   = u & 3;
        const int lane = (u >> 2) & 63;
        const int ks   = (u >> 8) & 1;
        const int mt   = u >> 9;
        const int ncol = mt * 16 + (lane & 15);
        const int k0   = ks * 32 + ((lane >> 4) << 3) + (i2 << 1);
        const float* W; int c; float sc = 1.f;
        if      (ncol <  64) { W = Wq;  c = ncol;       sc = QSCALE; }
        else if (ncol < 128) { W = Wk;  c = ncol - 64;  }
        else if (ncol < 192) { W = Wv;  c = ncol - 128; }
        else                 { W = Wsk; c = ncol - 192; }
        wpk[u] = packh2(W[k0 * 64 + c] * sc, W[(k0 + 1) * 64 + c] * sc);
    } else if (blockIdx.x == 32) {
        float b;
        if      (t <  64) b = bq[t] * QSCALE;
        else if (t < 128) b = bk[t - 64];
        else if (t < 192) b = bv[t - 128];
        else              b = bsk[t - 192];
        ball[t] = b;
    } else {
        __shared__ int h[256];
        h[t] = 0;
        __syncthreads();
        const int hb    = blockIdx.x - 33;
        const int chunk = (e_cnt + NH - 1) / NH;
        const int c0    = hb * chunk;
        const int c1    = min(c0 + chunk, e_cnt);
        for (int i = c0 + t; i < c1; i += 256)
            atomicAdd(&h[ei[e_cnt + i] >> BSH], 1);
        __syncthreads();
        if (h[t]) atomicAdd(&ghist[t], h[t]);
    }
}

// ---------------------------------------------------------------------------
// K1: fused linear + split kernel.
// Blocks [0, NLIN): MFMA q/k/v/skip linear.
// Blocks [NLIN, NLIN+NSPLIT): split edges into bucket regions (u8 bucket-id
//   LDS variant, 26 KB union).
// ---------------------------------------------------------------------------
__global__ __launch_bounds__(256) void k_linsplit(
    const float* __restrict__ x, const unsigned* __restrict__ wpk,
    const float* __restrict__ ball, const int* __restrict__ ei,
    const int* __restrict__ ghist, int* __restrict__ gcur0,
    unsigned* __restrict__ qh, unsigned* __restrict__ kvh,
    float* __restrict__ out, unsigned* __restrict__ epack,
    int n, int e_cnt, int NLIN)
{
    __shared__ __align__(16) union {
        struct {
            unsigned vals[SPLIT_CH];
            unsigned char bkt[SPLIT_CH];
            int hist[256], start[256], cur[256], base[256], s2[256], sg[256];
        } sp;
        _Float16 xsh[16][72];
    } sm;
    const int t = threadIdx.x;

    if (blockIdx.x >= NLIN) {
        // ---- split role ----
        unsigned* vals = sm.sp.vals;
        unsigned char* bkt = sm.sp.bkt;
        int* hist  = sm.sp.hist;
        int* start = sm.sp.start;
        int* cur   = sm.sp.cur;
        int* base  = sm.sp.base;
        int* s2    = sm.sp.s2;
        int* sg    = sm.sp.sg;

        const int e0  = (blockIdx.x - NLIN) * SPLIT_CH;
        const int cnt = min(SPLIT_CH, e_cnt - e0);

        hist[t] = 0;
        __syncthreads();
        for (int i = t; i < cnt; i += 256)
            atomicAdd(&hist[ei[e_cnt + e0 + i] >> BSH], 1);
        __syncthreads();

        {   // local exclusive scan + ghist self-scan + global reserve
            const int v = hist[t];
            const int g = ghist[t];
            s2[t] = v;
            sg[t] = g;
            __syncthreads();
            for (int off = 1; off < 256; off <<= 1) {
                const int a1 = (t >= off) ? s2[t - off] : 0;
                const int a2 = (t >= off) ? sg[t - off] : 0;
                __syncthreads();
                s2[t] += a1;
                sg[t] += a2;
                __syncthreads();
            }
            start[t] = s2[t] - v;
            cur[t]   = s2[t] - v;
            base[t]  = v ? (sg[t] - g + atomicAdd(&gcur0[t], v)) : 0;
        }
        __syncthreads();

        for (int i = t; i < cnt; i += 256) {
            const int s = ei[e0 + i];
            const int d = ei[e_cnt + e0 + i];
            const int b = d >> BSH;
            const int r = atomicAdd(&cur[b], 1);
            vals[r] = ((unsigned)s << BSH) | (unsigned)(d & 511);
            bkt[r]  = (unsigned char)b;
        }
        __syncthreads();

        for (int i = t; i < cnt; i += 256) {       // bucket-contiguous runs
            const int b = bkt[i];
            epack[base[b] + (i - start[b])] = vals[i];
        }
        return;
    }

    // ---- MFMA linear role ----
    const int node0 = blockIdx.x * 16;
    {
        const float4* xg = (const float4*)(x + (size_t)node0 * 64);
        const int row = t >> 4, c4 = (t & 15) << 2;
        if (node0 + row < n) {
            const float4 v = xg[t];
            f16x2* dst = (f16x2*)&sm.xsh[row][c4];
            dst[0] = f16x2{(_Float16)v.x, (_Float16)v.y};
            dst[1] = f16x2{(_Float16)v.z, (_Float16)v.w};
        }
    }
    __syncthreads();

    const int w  = t >> 6;      // wave: 0=q 1=k 2=v 3=skip
    const int l  = t & 63;
    const int nd = l & 15;      // node
    const int kg = l >> 4;      // k-group

    f32x4 acc0 = {0.f, 0.f, 0.f, 0.f};
    f32x4 acc1 = acc0, acc2 = acc0, acc3 = acc0;
    const uint4* wpk4 = (const uint4*)wpk;

#pragma unroll
    for (int ks = 0; ks < 2; ++ks) {
        const f16x8 bfrag = *(const f16x8*)&sm.xsh[nd][ks * 32 + kg * 8];
        const int fb = (w * 4 * 2 + ks) * 64 + l;
        const f16x8 a0 = __builtin_bit_cast(f16x8, wpk4[fb]);
        const f16x8 a1 = __builtin_bit_cast(f16x8, wpk4[fb + 128]);
        const f16x8 a2 = __builtin_bit_cast(f16x8, wpk4[fb + 256]);
        const f16x8 a3 = __builtin_bit_cast(f16x8, wpk4[fb + 384]);
        acc0 = __builtin_amdgcn_mfma_f32_16x16x32_f16(a0, bfrag, acc0, 0, 0, 0);
        acc1 = __builtin_amdgcn_mfma_f32_16x16x32_f16(a1, bfrag, acc1, 0, 0, 0);
        acc2 = __builtin_amdgcn_mfma_f32_16x16x32_f16(a2, bfrag, acc2, 0, 0, 0);
        acc3 = __builtin_amdgcn_mfma_f32_16x16x32_f16(a3, bfrag, acc3, 0, 0, 0);
    }

    const int node = node0 + nd;
    if (node >= n) return;

    f32x4 accs[4] = {acc0, acc1, acc2, acc3};
#pragma unroll
    for (int m4 = 0; m4 < 4; ++m4) {
        const int gc = (w * 4 + m4) * 16 + kg * 4;
        const float4 bb = ((const float4*)ball)[gc >> 2];
        const float v0 = accs[m4][0] + bb.x;
        const float v1 = accs[m4][1] + bb.y;
        const float v2 = accs[m4][2] + bb.z;
        const float v3 = accs[m4][3] + bb.w;
        if (w == 3) {
            ((float4*)out)[(size_t)node * 16 + ((gc - 192) >> 2)] =
                make_float4(v0, v1, v2, v3);
        } else {
            uint2 u;
            u.x = packh2(v0, v1);
            u.y = packh2(v2, v3);
            if (w == 0)
                ((uint2*)qh)[(size_t)node * 16 + (gc >> 2)] = u;
            else if (w == 1)
                ((uint2*)kvh)[(size_t)node * 32 + ((gc - 64) >> 2)] = u;
            else
                ((uint2*)kvh)[(size_t)node * 32 + 16 + ((gc - 128) >> 2)] = u;
        }
    }
}

// ---------------------------------------------------------------------------
// K3: per-bucket node sort (self-scans ghist for its bucket base).
// ---------------------------------------------------------------------------
__global__ __launch_bounds__(512) void k_nodesort(
    const unsigned* __restrict__ epack, const int* __restrict__ ghist,
    int* __restrict__ esrc, int* __restrict__ endoff, int n)
{
    __shared__ int h[512], cur[512], s[512];
    __shared__ int sbase;
    const int b = blockIdx.x;
    const int t = threadIdx.x;

    s[t] = (t < 256) ? ghist[t] : 0;
    __syncthreads();
    for (int off = 1; off < 512; off <<= 1) {
        const int add = (t >= off) ? s[t - off] : 0;
        __syncthreads();
        s[t] += add;
        __syncthreads();
    }
    if (t == 0) sbase = (b == 0) ? 0 : s[b - 1];
    __syncthreads();
    const int base = sbase;
    const int cnt  = ghist[b];

    h[t] = 0;
    __syncthreads();
    for (int i = t; i < cnt; i += 512)
        atomicAdd(&h[epack[base + i] & 511], 1);
    __syncthreads();

    const int v = h[t];
    s[t] = v;
    __syncthreads();
    for (int off = 1; off < 512; off <<= 1) {
        const int add = (t >= off) ? s[t - off] : 0;
        __syncthreads();
        s[t] += add;
        __syncthreads();
    }
    cur[t] = s[t] - v;
    const int node = (b << BSH) + t;
    if (node < n) endoff[node] = base + s[t];
    __syncthreads();

    for (int i = t; i < cnt; i += 512) {
        const unsigned p = epack[base + i];
        const int r = atomicAdd(&cur[p & 511], 1);
        esrc[base + r] = (int)(p >> BSH);
    }
}

// ---------------------------------------------------------------------------
// K5: attention, 8-lane edge groups, 16-edge-deep gather pipeline.
// ---------------------------------------------------------------------------
__global__ __launch_bounds__(256) void k_attn(
    const uint4* __restrict__ qh4, const uint4* __restrict__ kv4,
    const int* __restrict__ endoff, const int* __restrict__ esrc,
    float* __restrict__ out, int n)
{
    const int t = threadIdx.x;
    const int node = blockIdx.x * 4 + (t >> 6);
    if (node >= n) return;
    const int lane = t & 63;
    const int g = lane >> 3;     // edge group
    const int l = lane & 7;      // dim chunk

    const int beg = (node == 0) ? 0 : endoff[node - 1];
    const int end = endoff[node];
    const int last = end - 1;

    float4 o0 = make_float4(0.f, 0.f, 0.f, 0.f);
    float4 o1 = o0;
    if (g == 0) {
        o0 = ((const float4*)out)[(size_t)node * 16 + 2 * l];
        o1 = ((const float4*)out)[(size_t)node * 16 + 2 * l + 1];
    }

    const uint4 qu = qh4[(size_t)node * 8 + l];
    const f16x2* qp = (const f16x2*)&qu;

    f16x2 a0 = {(_Float16)0.f, (_Float16)0.f};
    f16x2 a1 = a0, a2 = a0, a3 = a0;
    float den = 0.f;

    int b2 = beg;
    for (; end - b2 > 8; b2 += 16) {
        const int iA = b2 + 2 * g;
        const int iB = iA + 1;
        const int sA = esrc[min(iA, last)];
        const int sB = esrc[min(iB, last)];
        const uint4 kuA = kv4[(size_t)sA * 16 + l];
        const uint4 vuA = kv4[(size_t)sA * 16 + 8 + l];
        const uint4 kuB = kv4[(size_t)sB * 16 + l];
        const uint4 vuB = kv4[(size_t)sB * 16 + 8 + l];
        const f16x2* kpA = (const f16x2*)&kuA;
        const f16x2* vpA = (const f16x2*)&vuA;
        const f16x2* kpB = (const f16x2*)&kuB;
        const f16x2* vpB = (const f16x2*)&vuB;

        float dA = fdot2f(qp[0], kpA[0], 0.f);
        float dB = fdot2f(qp[0], kpB[0], 0.f);
        dA = fdot2f(qp[1], kpA[1], dA);
        dB = fdot2f(qp[1], kpB[1], dB);
        dA = fdot2f(qp[2], kpA[2], dA);
        dB = fdot2f(qp[2], kpB[2], dB);
        dA = fdot2f(qp[3], kpA[3], dA);
        dB = fdot2f(qp[3], kpB[3], dB);
        dA += __shfl_xor(dA, 1);  dB += __shfl_xor(dB, 1);
        dA += __shfl_xor(dA, 2);  dB += __shfl_xor(dB, 2);
        dA += __shfl_xor(dA, 4);  dB += __shfl_xor(dB, 4);

        const float eA = (iA < end) ? exp2f(dA) : 0.f;
        const float eB = (iB < end) ? exp2f(dB) : 0.f;
        den += eA + eB;
        const _Float16 ehA = (_Float16)eA;
        const _Float16 ehB = (_Float16)eB;
        const f16x2 e2A = {ehA, ehA};
        const f16x2 e2B = {ehB, ehB};
        a0 += e2A * vpA[0];  a0 += e2B * vpB[0];
        a1 += e2A * vpA[1];  a1 += e2B * vpB[1];
        a2 += e2A * vpA[2];  a2 += e2B * vpB[2];
        a3 += e2A * vpA[3];  a3 += e2B * vpB[3];
    }
    for (; b2 < end; b2 += 8) {
        const int i = b2 + g;
        const int s = esrc[min(i, last)];
        const uint4 ku = kv4[(size_t)s * 16 + l];
        const uint4 vu = kv4[(size_t)s * 16 + 8 + l];
        const f16x2* kp = (const f16x2*)&ku;
        const f16x2* vp = (const f16x2*)&vu;

        float d = fdot2f(qp[0], kp[0], 0.f);
        d = fdot2f(qp[1], kp[1], d);
        d = fdot2f(qp[2], kp[2], d);
        d = fdot2f(qp[3], kp[3], d);
        d += __shfl_xor(d, 1);
        d += __shfl_xor(d, 2);
        d += __shfl_xor(d, 4);

        const float e = (i < end) ? exp2f(d) : 0.f;
        den += e;
        const _Float16 eh = (_Float16)e;
        const f16x2 e2 = {eh, eh};
        a0 += e2 * vp[0];
        a1 += e2 * vp[1];
        a2 += e2 * vp[2];
        a3 += e2 * vp[3];
    }

#pragma unroll
    for (int m = 8; m <= 32; m <<= 1) {
        den += __shfl_xor(den, m);
        a0 += shxor_h2(a0, m);
        a1 += shxor_h2(a1, m);
        a2 += shxor_h2(a2, m);
        a3 += shxor_h2(a3, m);
    }

    if (g == 0) {
        const float inv = 1.f / (den + 1e-16f);
        float4 r0, r1;
        r0.x = o0.x + (float)a0.x * inv;
        r0.y = o0.y + (float)a0.y * inv;
        r0.z = o0.z + (float)a1.x * inv;
        r0.w = o0.w + (float)a1.y * inv;
        r1.x = o1.x + (float)a2.x * inv;
        r1.y = o1.y + (float)a2.y * inv;
        r1.z = o1.z + (float)a3.x * inv;
        r1.w = o1.w + (float)a3.y * inv;
        ((float4*)out)[(size_t)node * 16 + 2 * l]     = r0;
        ((float4*)out)[(size_t)node * 16 + 2 * l + 1] = r1;
    }
}

// ---------------------------------------------------------------------------
extern "C" void kernel_launch(void* const* d_in, const int* in_sizes, int n_in,
                              void* d_out, int out_size, void* d_ws, size_t ws_size,
                              hipStream_t stream)
{
    const float* x   = (const float*)d_in[0];
    const int*   ei  = (const int*)d_in[1];
    // d_in[2] = edge_type, unused by the reference forward
    const float* Wq  = (const float*)d_in[3];
    const float* bq  = (const float*)d_in[4];
    const float* Wk  = (const float*)d_in[5];
    const float* bk  = (const float*)d_in[6];
    const float* Wv  = (const float*)d_in[7];
    const float* bv  = (const float*)d_in[8];
    const float* Wsk = (const float*)d_in[9];
    const float* bsk = (const float*)d_in[10];
    float* out = (float*)d_out;

    const int n      = in_sizes[0] / D;   // 100000
    const int e_cnt  = in_sizes[1] / 2;   // 1200000
    const int nbkt   = (n + 511) >> BSH;  // 196 (<= 256)
    const int NLIN   = (n + 15) / 16;     // MFMA-linear blocks
    const int NSPLIT = (e_cnt + SPLIT_CH - 1) / SPLIT_CH;

    // workspace layout
    unsigned* qh     = (unsigned*)d_ws;                   // n*32 u32
    unsigned* kvh    = qh + (size_t)n * 32;               // n*64 u32
    int*      esrc   = (int*)(kvh + (size_t)n * 64);
    unsigned* epack  = (unsigned*)(esrc + e_cnt);
    int*      endoff = (int*)(epack + e_cnt);
    int*      ghist  = endoff + n;
    int*      gcur0  = ghist + 256;
    float*    ball   = (float*)(gcur0 + 256);
    unsigned* wpk    = (unsigned*)(ball + 256);           // 8192 u32

    hipMemsetAsync(ghist, 0, 512 * sizeof(int), stream);  // ghist + gcur0

    k_prep<<<33 + NH, 256, 0, stream>>>(
        Wq, Wk, Wv, Wsk, bq, bk, bv, bsk, ei, wpk, ball, ghist, e_cnt);

    k_linsplit<<<NLIN + NSPLIT, 256, 0, stream>>>(
        x, wpk, ball, ei, ghist, gcur0, qh, kvh, out, epack, n, e_cnt, NLIN);

    k_nodesort<<<nbkt, 512, 0, stream>>>(
        epack, ghist, esrc, endoff, n);

    k_attn<<<(n + 3) / 4, 256, 0, stream>>>(
        (const uint4*)qh, (const uint4*)kvh, endoff, esrc, out, n);
}